// Round 3
// baseline (1096.459 us; speedup 1.0000x reference)
//
#include <hip/hip_runtime.h>
#include <hip/hip_bf16.h>
#include <stdint.h>
#include <stddef.h>

#define N_NODES 30000
#define N_EDGES 480000
#define EN_TOT  (N_EDGES + N_NODES)   /* 510000 with self loops */
#define F_IN 4096
#define HEADS 4
#define HID 128
#define D1 (HEADS * HID)              /* 512 */
#define CLS 6
#define NEG_SLOPE 0.2f

typedef __attribute__((ext_vector_type(4))) unsigned int u32x4;
typedef __attribute__((ext_vector_type(8))) short short8;
typedef __attribute__((ext_vector_type(4))) float f32x4;

__device__ __forceinline__ float bf2f(unsigned short u) {
  return __uint_as_float(((unsigned int)u) << 16);
}
__device__ __forceinline__ unsigned short f2bf(float f) {
  unsigned int u = __float_as_uint(f);
  unsigned int r = (u + 0x7FFFu + ((u >> 16) & 1u)) >> 16;  // RNE
  return (unsigned short)r;
}
__device__ __forceinline__ float ldin(const void* p, int isbf, size_t i) {
  if (isbf) return bf2f(((const unsigned short*)p)[i]);
  return ((const float*)p)[i];
}

// async 16B global -> LDS (wave-uniform LDS base + lane*16, per-lane global addr)
__device__ __forceinline__ void gload_lds16(const void* g, void* l) {
  __builtin_amdgcn_global_load_lds(
      (const __attribute__((address_space(1))) unsigned int*)g,
      (__attribute__((address_space(3))) unsigned int*)l,
      16, 0, 0);
}

// ---------------------------------------------------------------- dtype detect
__global__ void k_detect(const void* xraw, int* flag) {
  __shared__ int bad;
  if (threadIdx.x == 0) bad = 0;
  __syncthreads();
  const unsigned short* u = (const unsigned short*)xraw;
  int cnt = 0;
  for (int i = threadIdx.x; i < 8192; i += 256) {
    float v = bf2f(u[i]);
    if (!isfinite(v) || fabsf(v) > 1e8f) cnt++;
  }
  atomicAdd(&bad, cnt);
  __syncthreads();
  if (threadIdx.x == 0) *flag = (bad > 8) ? 0 : 1;  // 1 = bf16 mode
}

// ---------------------------------------------------------------- zero fill (deg only)
__global__ void k_zero(int* __restrict__ p, int n) {
  int i = blockIdx.x * blockDim.x + threadIdx.x;
  if (i < n) p[i] = 0;
}

// ---------------------------------------------------------------- CSR build
__global__ void k_hist(const int* __restrict__ ei, int* __restrict__ deg) {
  int i = blockIdx.x * blockDim.x + threadIdx.x;
  if (i >= EN_TOT) return;
  int d = (i < N_EDGES) ? ei[N_EDGES + i] : i - N_EDGES;
  atomicAdd(&deg[d], 1);
}

// single-block exclusive scan over 30000 degrees -> offs[30001], cursor copy
__global__ void k_scan(const int* __restrict__ deg, int* __restrict__ offs,
                       int* __restrict__ cursor) {
  __shared__ int sums[1024];
  const int tid = threadIdx.x;
  const int CH = (N_NODES + 1023) / 1024;  // 30
  int base = tid * CH;
  int local = 0;
  for (int j = 0; j < CH; j++) {
    int idx = base + j;
    if (idx < N_NODES) local += deg[idx];
  }
  sums[tid] = local;
  __syncthreads();
  for (int off = 1; off < 1024; off <<= 1) {
    int v = (tid >= off) ? sums[tid - off] : 0;
    __syncthreads();
    sums[tid] += v;
    __syncthreads();
  }
  int run = (tid == 0) ? 0 : sums[tid - 1];
  for (int j = 0; j < CH; j++) {
    int idx = base + j;
    if (idx < N_NODES) {
      offs[idx] = run;
      cursor[idx] = run;
      run += deg[idx];
    }
  }
  if (tid == 1023) offs[N_NODES] = sums[1023];
}

__global__ void k_scatter(const int* __restrict__ ei, int* __restrict__ cursor,
                          int* __restrict__ csr_src) {
  int i = blockIdx.x * blockDim.x + threadIdx.x;
  if (i >= EN_TOT) return;
  int s, d;
  if (i < N_EDGES) { s = ei[i]; d = ei[N_EDGES + i]; }
  else { s = d = i - N_EDGES; }
  int pos = atomicAdd(&cursor[d], 1);
  csr_src[pos] = s;
}

// ---------------------------------------------------------------- W1 transpose: [F_IN, D1] -> bf16 [D1, F_IN]
__global__ void k_transpose(const void* __restrict__ in, unsigned short* __restrict__ out,
                            const int* __restrict__ flag) {
  const int isbf = *flag;
  __shared__ unsigned short t[32][33];
  int bx = blockIdx.x * 32;
  int by = blockIdx.y * 32;
  int x = threadIdx.x, y = threadIdx.y;  // 32 x 8
#pragma unroll
  for (int i = 0; i < 32; i += 8)
    t[y + i][x] = f2bf(ldin(in, isbf, (size_t)(by + y + i) * D1 + bx + x));
  __syncthreads();
#pragma unroll
  for (int i = 0; i < 32; i += 8)
    out[(size_t)(bx + y + i) * F_IN + by + x] = t[x][y + i];
}

// ---------------------------------------------------------------- GEMM1: h1[30000,512] = x @ W1 (bf16 MFMA)
// BM=64, BN=512 (x streamed ONCE), BK=32.
// 256 threads = 4 waves as 1(M) x 4(N); wave tile 64x128 (wave == head).
// 2 blocks/CU + 2-phase double-buffer prefetch.
// Fused: per-row alpha_src/alpha_dst (a_s,a_d dot) in epilogue.
__launch_bounds__(256, 2)
__global__ void k_gemm1(const void* __restrict__ xraw, const unsigned short* __restrict__ w1t,
                        unsigned short* __restrict__ h1,
                        const void* __restrict__ a_s, const void* __restrict__ a_d,
                        float* __restrict__ as1, float* __restrict__ ad1,
                        const int* __restrict__ flag) {
  const int isbf = *flag;
  __shared__ __align__(16) unsigned short As[2][64 * 32];    // 2 x 4 KB
  __shared__ __align__(16) unsigned short Bs[2][512 * 32];   // 2 x 32 KB
  const int tid = threadIdx.x;
  const int wave = tid >> 6, lane = tid & 63;
  const int l15 = lane & 15, lq = lane >> 4;
  const int wn = wave * 128;          // wave col offset == head*HID
  const int m0 = blockIdx.x * 64;

  // A staging: unit = tid; row tid>>2, 8 cols at (tid&3)*8
  int arow = m0 + (tid >> 2);
  if (arow >= N_NODES) arow = N_NODES - 1;  // clamp; OOB rows discarded at store
  const int c8 = (tid & 3) * 8;
  const unsigned short* agA  = (const unsigned short*)xraw + (size_t)arow * F_IN + c8;
  const float*          agAf = (const float*)xraw + (size_t)arow * F_IN + c8;
  // B staging: 8 chunks of 256 units; chunk ch covers rows ch*64 + (tid>>2)
  const unsigned short* agB = w1t + (size_t)(tid >> 2) * F_IN + c8;

  f32x4 acc[4][8];
#pragma unroll
  for (int i = 0; i < 4; i++)
#pragma unroll
    for (int j = 0; j < 8; j++) acc[i][j] = (f32x4){0.f, 0.f, 0.f, 0.f};

  auto stage = [&](int buf, int k0) {
    if (isbf) {
      gload_lds16(agA + k0, &As[buf][wave * 512]);
    } else {
      float4 v0 = *(const float4*)(agAf + k0);
      float4 v1 = *(const float4*)(agAf + k0 + 4);
      u32x4 av;
      av[0] = (unsigned int)f2bf(v0.x) | ((unsigned int)f2bf(v0.y) << 16);
      av[1] = (unsigned int)f2bf(v0.z) | ((unsigned int)f2bf(v0.w) << 16);
      av[2] = (unsigned int)f2bf(v1.x) | ((unsigned int)f2bf(v1.y) << 16);
      av[3] = (unsigned int)f2bf(v1.z) | ((unsigned int)f2bf(v1.w) << 16);
      ((u32x4*)As[buf])[tid] = av;
    }
#pragma unroll
    for (int ch = 0; ch < 8; ch++)
      gload_lds16(agB + (size_t)ch * 64 * F_IN + k0, &Bs[buf][ch * 2048 + wave * 512]);
  };

  auto compute = [&](int buf) {
    const u32x4* As4 = (const u32x4*)As[buf];
    const u32x4* Bs4 = (const u32x4*)Bs[buf];
    short8 af[4], bfr[8];
#pragma unroll
    for (int i = 0; i < 4; i++)
      af[i] = __builtin_bit_cast(short8, As4[(16 * i + l15) * 4 + lq]);
#pragma unroll
    for (int j = 0; j < 8; j++)
      bfr[j] = __builtin_bit_cast(short8, Bs4[(wn + 16 * j + l15) * 4 + lq]);
#pragma unroll
    for (int i = 0; i < 4; i++)
#pragma unroll
      for (int j = 0; j < 8; j++)
        acc[i][j] = __builtin_amdgcn_mfma_f32_16x16x32_bf16(af[i], bfr[j], acc[i][j], 0, 0, 0);
  };

  stage(0, 0);
  __syncthreads();
  int cur = 0;
  for (int t = 0; t < F_IN / 32 - 1; ++t) {
    stage(cur ^ 1, (t + 1) * 32);   // async loads in flight during compute
    compute(cur);
    __syncthreads();                 // drains vmcnt+lgkmcnt, flips buffer
    cur ^= 1;
  }
  compute(cur);

  // ---- epilogue: store h1 + fused per-row attention coefficients ----
  float asv[8], adv[8];
#pragma unroll
  for (int j = 0; j < 8; j++) {
    asv[j] = ldin(a_s, isbf, wave * HID + 16 * j + l15);
    adv[j] = ldin(a_d, isbf, wave * HID + 16 * j + l15);
  }
#pragma unroll
  for (int i = 0; i < 4; i++) {
#pragma unroll
    for (int r = 0; r < 4; r++) {
      int row = m0 + 16 * i + lq * 4 + r;
      bool ok = row < N_NODES;
      float s0 = 0.f, s1 = 0.f;
#pragma unroll
      for (int j = 0; j < 8; j++) {
        float v = acc[i][j][r];
        if (ok) h1[(size_t)row * D1 + wn + 16 * j + l15] = f2bf(v);
        s0 += v * asv[j];
        s1 += v * adv[j];
      }
#pragma unroll
      for (int off = 1; off < 16; off <<= 1) {
        s0 += __shfl_xor(s0, off, 16);
        s1 += __shfl_xor(s1, off, 16);
      }
      if (ok && l15 == 0) {
        as1[row * HEADS + wave] = s0;
        ad1[row * HEADS + wave] = s1;
      }
    }
  }
}

// ---------------------------------------------------------------- aggregation layer 1, CSR gather, FUSED edge-softmax + layer2 linear
// block = 128 threads = one dst node; thread t covers channels 4t..4t+3 (one head).
// p(s,d) computed in-staging from as1/ad1 (no p1 buffer, no eid).
// Epilogue: x2 = elu(agg+b1); h2 = x2 @ W2; as2/ad2 coeffs.
#define CHUNK 256
__launch_bounds__(128, 8)
__global__ void k_agg1_csr(const int* __restrict__ offs, const int* __restrict__ csr_src,
                           const float* __restrict__ as1, const float* __restrict__ ad1,
                           const unsigned short* __restrict__ h1,
                           const void* __restrict__ b1, const void* __restrict__ w2,
                           const void* __restrict__ a_s2, const void* __restrict__ a_d2,
                           float* __restrict__ h2, float* __restrict__ as2,
                           float* __restrict__ ad2, const int* __restrict__ flag) {
  __shared__ int s_src[CHUNK];
  __shared__ float4 s_p[CHUNK];
  __shared__ float red[2][CLS];
  const int isbf = *flag;
  const int n = blockIdx.x;
  const int tid = threadIdx.x;
  const int c = tid * 4;
  const int h = tid >> 5;            // head = c>>7
  const int start = offs[n], end = offs[n + 1];
  const float4 adn = *(const float4*)(ad1 + (size_t)n * HEADS);  // block-uniform
  float a0 = 0.f, a1 = 0.f, a2 = 0.f, a3 = 0.f, dsum = 0.f;
  for (int base = start; base < end; base += CHUNK) {
    int cnt = end - base;
    if (cnt > CHUNK) cnt = CHUNK;
    for (int idx = tid; idx < cnt; idx += 128) {
      int s = csr_src[base + idx];
      s_src[idx] = s;
      float4 av = *(const float4*)(as1 + (size_t)s * HEADS);
      float4 pv;
#pragma unroll
      for (int hh = 0; hh < 4; ++hh) {
        float e = ((const float*)&av)[hh] + ((const float*)&adn)[hh];
        e = e > 0.f ? e : NEG_SLOPE * e;
        ((float*)&pv)[hh] = __expf(e);
      }
      s_p[idx] = pv;
    }
    __syncthreads();
    for (int j = 0; j < cnt; ++j) {
      int s = s_src[j];
      float p = ((const float*)&s_p[j])[h];   // wave-uniform h -> LDS broadcast
      const unsigned short* hp = h1 + (size_t)s * D1 + c;
      uint2 hv = *(const uint2*)hp;           // 4 bf16
      a0 += p * bf2f((unsigned short)(hv.x & 0xFFFFu));
      a1 += p * bf2f((unsigned short)(hv.x >> 16));
      a2 += p * bf2f((unsigned short)(hv.y & 0xFFFFu));
      a3 += p * bf2f((unsigned short)(hv.y >> 16));
      dsum += p;
    }
    __syncthreads();
  }
  float inv = 1.f / dsum;   // self-loop guarantees dsum > 0
  // fused layer-2 input: elu(agg + b1), 4 channels per thread
  float xv[4] = {a0, a1, a2, a3};
  float t6[CLS] = {0.f, 0.f, 0.f, 0.f, 0.f, 0.f};
#pragma unroll
  for (int q = 0; q < 4; ++q) {
    float xq = xv[q] * inv + ldin(b1, isbf, c + q);
    xq = xq > 0.f ? xq : (__expf(xq) - 1.f);
#pragma unroll
    for (int j = 0; j < CLS; ++j)
      t6[j] += xq * ldin(w2, isbf, (size_t)(c + q) * CLS + j);
  }
#pragma unroll
  for (int off = 32; off > 0; off >>= 1)
#pragma unroll
    for (int j = 0; j < CLS; ++j) t6[j] += __shfl_down(t6[j], off, 64);
  int wv = tid >> 6, ln = tid & 63;
  if (ln == 0)
#pragma unroll
    for (int j = 0; j < CLS; ++j) red[wv][j] = t6[j];
  __syncthreads();
  if (tid == 0) {
    float s0 = 0.f, s1 = 0.f;
#pragma unroll
    for (int j = 0; j < CLS; ++j) {
      float v = red[0][j] + red[1][j];
      h2[(size_t)n * CLS + j] = v;
      s0 += v * ldin(a_s2, isbf, j);
      s1 += v * ldin(a_d2, isbf, j);
    }
    as2[n] = s0;
    ad2[n] = s1;
  }
}

// ---------------------------------------------------------------- aggregation layer 2, CSR, FUSED edge-softmax + bias + output store
// wave per node; lanes stride over edges; p(s,d) computed inline.
__global__ void k_agg2_csr(const int* __restrict__ offs, const int* __restrict__ csr_src,
                           const float* __restrict__ as2, const float* __restrict__ ad2,
                           const float* __restrict__ h2, const void* __restrict__ b2,
                           void* __restrict__ out, const int* __restrict__ flag) {
  const int isbf = *flag;
  int wave = threadIdx.x >> 6, lane = threadIdx.x & 63;
  int n = blockIdx.x * 4 + wave;
  if (n >= N_NODES) return;
  int start = offs[n], end = offs[n + 1];
  const float ad2n = ad2[n];
  float acc[CLS] = {0.f, 0.f, 0.f, 0.f, 0.f, 0.f};
  float dsum = 0.f;
  for (int e = start + lane; e < end; e += 64) {
    int s = csr_src[e];
    float ev = as2[s] + ad2n;
    ev = ev > 0.f ? ev : NEG_SLOPE * ev;
    float p = __expf(ev);
    dsum += p;
    const float* hp = h2 + (size_t)s * CLS;
#pragma unroll
    for (int c = 0; c < CLS; ++c) acc[c] += p * hp[c];
  }
#pragma unroll
  for (int off = 32; off > 0; off >>= 1) {
    dsum += __shfl_down(dsum, off, 64);
#pragma unroll
    for (int c = 0; c < CLS; ++c) acc[c] += __shfl_down(acc[c], off, 64);
  }
  if (lane == 0) {
    float inv = 1.f / dsum;
#pragma unroll
    for (int c = 0; c < CLS; ++c) {
      float v = acc[c] * inv + ldin(b2, isbf, c);
      if (isbf) ((unsigned short*)out)[n * CLS + c] = f2bf(v);
      else      ((float*)out)[n * CLS + c] = v;
    }
  }
}

// ================================================================ launch
extern "C" void kernel_launch(void* const* d_in, const int* in_sizes, int n_in,
                              void* d_out, int out_size, void* d_ws, size_t ws_size,
                              hipStream_t stream) {
  const void* x    = d_in[0];
  const int*  ei   = (const int*)d_in[1];
  const void* W1   = d_in[2];
  const void* a_s1 = d_in[3];
  const void* a_d1 = d_in[4];
  const void* b1   = d_in[5];
  const void* W2   = d_in[6];
  const void* a_s2 = d_in[7];
  const void* a_d2 = d_in[8];
  const void* b2   = d_in[9];

  char* ws = (char*)d_ws;
  size_t off = 0;
  auto alloc = [&](size_t b) { size_t r = off; off += (b + 255) & ~(size_t)255; return r; };
  int*   flag    = (int*)(ws + alloc(256));
  unsigned short* w1t = (unsigned short*)(ws + alloc((size_t)D1 * F_IN * 2));
  unsigned short* h1  = (unsigned short*)(ws + alloc((size_t)N_NODES * D1 * 2));
  float* as1     = (float*)(ws + alloc((size_t)N_NODES * HEADS * 4));
  float* ad1     = (float*)(ws + alloc((size_t)N_NODES * HEADS * 4));
  float* as2v    = (float*)(ws + alloc((size_t)N_NODES * 4));
  float* ad2v    = (float*)(ws + alloc((size_t)N_NODES * 4));
  float* h2      = (float*)(ws + alloc((size_t)N_NODES * CLS * 4));
  int*   deg     = (int*)(ws + alloc((size_t)N_NODES * 4));
  int*   offs    = (int*)(ws + alloc((size_t)(N_NODES + 1) * 4));
  int*   cursor  = (int*)(ws + alloc((size_t)N_NODES * 4));
  int*   csr_src = (int*)(ws + alloc((size_t)EN_TOT * 4));

  int eb = (EN_TOT + 255) / 256;
  k_detect<<<1, 256, 0, stream>>>(x, flag);
  k_zero<<<(N_NODES + 255) / 256, 256, 0, stream>>>(deg, N_NODES);
  k_hist<<<eb, 256, 0, stream>>>(ei, deg);
  k_scan<<<1, 1024, 0, stream>>>(deg, offs, cursor);
  k_scatter<<<eb, 256, 0, stream>>>(ei, cursor, csr_src);
  k_transpose<<<dim3(D1 / 32, F_IN / 32), dim3(32, 8), 0, stream>>>(W1, w1t, flag);
  k_gemm1<<<dim3((N_NODES + 63) / 64), 256, 0, stream>>>(x, w1t, h1, a_s1, a_d1,
                                                         as1, ad1, flag);
  k_agg1_csr<<<N_NODES, 128, 0, stream>>>(offs, csr_src, as1, ad1, h1,
                                          b1, W2, a_s2, a_d2, h2, as2v, ad2v, flag);
  k_agg2_csr<<<(N_NODES + 3) / 4, 256, 0, stream>>>(offs, csr_src, as2v, ad2v, h2, b2,
                                                    d_out, flag);
}